// Round 1
// baseline (2328.297 us; speedup 1.0000x reference)
//
#include <hip/hip_runtime.h>
#include <hip/hip_fp16.h>

// ---------------------------------------------------------------------------
// GenomeDecoder: transformer encoder (tiny) -> 1028 sequential GRU steps ->
// output chunks.  Key restructure: fold chunk-feedback (x_t = out_W@h_t+out_b)
// into the recurrence, pre-sum r/z gate rows -> one 1024x256 f16 matvec per
// step, weights register/LDS-resident per CU (16 CUs = 16 batch chains).
// out_W matvec moved off critical path into a parallel epilogue GEMM.
// ---------------------------------------------------------------------------

typedef _Float16 f16x2 __attribute__((ext_vector_type(2)));
typedef unsigned int uint_t;

// ---- workspace layout (float indices) ----
// Hb   [16][16][256]      transformer activations
// QKV  [16][16][768]
// AO   [16][16][256]
// F1   [16][16][1024]
// LAT  [16][256]
// GI0  [16][768]          Wih@latent + bih  (step-0 input)
// CV   [1024]             per-row constants of fused matrix
// M    [1024][128] dwords (f16x2 packed fused matrix, row-major)
// HSEQ [1028][16][256]    h_{t+1} for epilogue
static constexpr size_t WS_HB   = 0;
static constexpr size_t WS_QKV  = 65536;
static constexpr size_t WS_AO   = 262144;
static constexpr size_t WS_F1   = 327680;
static constexpr size_t WS_LAT  = 589824;
static constexpr size_t WS_GI0  = 593920;
static constexpr size_t WS_CV   = 606208;
static constexpr size_t WS_M    = 607232;   // 131072 dword slots
static constexpr size_t WS_HSEQ = 738304;   // 1028*4096 floats

#if defined(__has_builtin)
#if __has_builtin(__builtin_amdgcn_fdot2)
#define HAVE_FDOT2 1
#endif
#endif

__device__ inline f16x2 u2h(uint_t u){ union{uint_t u; f16x2 h;} c; c.u=u; return c.h; }

__device__ inline float dot2f(uint_t w, uint_t h, float acc){
#ifdef HAVE_FDOT2
    return __builtin_amdgcn_fdot2(u2h(w), u2h(h), acc, false);
#else
    f16x2 a=u2h(w), b=u2h(h);
    return acc + (float)a.x*(float)b.x + (float)a.y*(float)b.y;
#endif
}

__device__ inline unsigned short f2hb(float x){
    union{ _Float16 h; unsigned short u; } c; c.h = (_Float16)x; return c.u;
}
__device__ inline float sigf(float x){ return 1.0f/(1.0f+__expf(-x)); }
__device__ inline float tanh_fast(float x){ float e=__expf(2.0f*x); return (e-1.0f)/(e+1.0f); }

// ======================= transformer front-end =============================

__global__ __launch_bounds__(256) void k_embed(const float* gs, const float* eW,
                                               const float* eb, float* ws){
    int bs = blockIdx.x;            // b*16+s
    int i  = threadIdx.x;
    const float* g = gs + bs*16;
    float acc = eb[i];
#pragma unroll
    for(int d=0; d<16; ++d) acc += g[d]*eW[i*16+d];
    ws[WS_HB + (size_t)bs*256 + i] = acc;
}

__global__ __launch_bounds__(256) void k_qkv(const float* qkvW, const float* qkvb,
                                             float* ws, int l){
    __shared__ float hr[16][256];
    int b = blockIdx.x, jc = blockIdx.y;
    for(int idx=threadIdx.x; idx<4096; idx+=256)
        hr[idx>>8][idx&255] = ws[WS_HB + (size_t)(b*16+(idx>>8))*256 + (idx&255)];
    __syncthreads();
    int j = jc*256 + threadIdx.x;
    float bias = qkvb[l*768 + j];
    float acc[16];
#pragma unroll
    for(int s=0;s<16;++s) acc[s]=bias;
    const float* wr = qkvW + (size_t)(l*768 + j)*256;
    for(int k=0;k<256;k+=4){
        float4 w4 = *(const float4*)(wr+k);
#pragma unroll
        for(int s=0;s<16;++s)
            acc[s] += w4.x*hr[s][k] + w4.y*hr[s][k+1] + w4.z*hr[s][k+2] + w4.w*hr[s][k+3];
    }
    for(int s=0;s<16;++s) ws[WS_QKV + (size_t)(b*16+s)*768 + j] = acc[s];
}

__global__ __launch_bounds__(256) void k_attn(float* ws){
    __shared__ float ql[16][64], kl[16][64], vl[16][64], sc[16][16];
    int b = blockIdx.x>>2, hh = blockIdx.x&3;
    for(int idx=threadIdx.x; idx<1024; idx+=256){
        int s_=idx>>6, d=idx&63;
        const float* base = &ws[WS_QKV + (size_t)(b*16+s_)*768 + hh*64 + d];
        ql[s_][d]=base[0]; kl[s_][d]=base[256]; vl[s_][d]=base[512];
    }
    __syncthreads();
    int s = threadIdx.x>>4, t = threadIdx.x&15;
    float a=0.f;
#pragma unroll
    for(int d=0; d<64; ++d) a += ql[s][d]*kl[t][d];
    sc[s][t] = a*0.125f;
    __syncthreads();
    if(threadIdx.x<16){
        int r=threadIdx.x;
        float m=-1e30f;
#pragma unroll
        for(int tt=0;tt<16;++tt) m=fmaxf(m,sc[r][tt]);
        float e[16]; float sum=0.f;
#pragma unroll
        for(int tt=0;tt<16;++tt){ e[tt]=__expf(sc[r][tt]-m); sum+=e[tt]; }
        float inv=1.0f/sum;
#pragma unroll
        for(int tt=0;tt<16;++tt) sc[r][tt]=e[tt]*inv;
    }
    __syncthreads();
    int dg = (threadIdx.x&15)*4;
#pragma unroll
    for(int dd=0;dd<4;++dd){
        int d = dg+dd; float o=0.f;
#pragma unroll
        for(int tt=0;tt<16;++tt) o += sc[s][tt]*vl[tt][d];
        ws[WS_AO + (size_t)(b*16+s)*256 + hh*64 + d] = o;
    }
}

__global__ __launch_bounds__(256) void k_ao_ln(const float* aoW, const float* aob,
                                               const float* g1, const float* b1,
                                               float* ws, int l){
    __shared__ float ao[256]; __shared__ float red[256];
    int bs = blockIdx.x, i = threadIdx.x;
    ao[i] = ws[WS_AO + (size_t)bs*256 + i];
    __syncthreads();
    const float* wr = aoW + (size_t)(l*256+i)*256;
    float acc = aob[l*256+i];
    for(int k=0;k<256;k+=4){
        float4 w4 = *(const float4*)(wr+k);
        acc += w4.x*ao[k]+w4.y*ao[k+1]+w4.z*ao[k+2]+w4.w*ao[k+3];
    }
    float x = ws[WS_HB + (size_t)bs*256 + i] + acc;
    red[i]=x; __syncthreads();
    for(int off=128;off>0;off>>=1){ if(i<off) red[i]+=red[i+off]; __syncthreads(); }
    float m = red[0]*(1.0f/256.0f); __syncthreads();
    float d = x-m;
    red[i]=d*d; __syncthreads();
    for(int off=128;off>0;off>>=1){ if(i<off) red[i]+=red[i+off]; __syncthreads(); }
    float v = red[0]*(1.0f/256.0f);
    float y = d / sqrtf(v+1e-5f);
    ws[WS_HB + (size_t)bs*256 + i] = y*g1[l*256+i] + b1[l*256+i];
}

__global__ __launch_bounds__(256) void k_ffn1(const float* W1, const float* fb1,
                                              float* ws, int l){
    __shared__ float hr[16][256];
    int b = blockIdx.x, jc = blockIdx.y;
    for(int idx=threadIdx.x; idx<4096; idx+=256)
        hr[idx>>8][idx&255] = ws[WS_HB + (size_t)(b*16+(idx>>8))*256 + (idx&255)];
    __syncthreads();
    int j = jc*256 + threadIdx.x;
    float bias = fb1[l*1024+j];
    float acc[16];
#pragma unroll
    for(int s=0;s<16;++s) acc[s]=bias;
    const float* wr = W1 + (size_t)(l*1024+j)*256;
    for(int k=0;k<256;k+=4){
        float4 w4 = *(const float4*)(wr+k);
#pragma unroll
        for(int s=0;s<16;++s)
            acc[s] += w4.x*hr[s][k] + w4.y*hr[s][k+1] + w4.z*hr[s][k+2] + w4.w*hr[s][k+3];
    }
    for(int s=0;s<16;++s)
        ws[WS_F1 + (size_t)(b*16+s)*1024 + j] = fmaxf(acc[s],0.0f);
}

__global__ __launch_bounds__(256) void k_ffn2_ln(const float* W2, const float* fb2,
                                                 const float* g2, const float* b2v,
                                                 float* ws, int l){
    __shared__ float f1r[1024]; __shared__ float red[256];
    int bs = blockIdx.x, i = threadIdx.x;
    for(int idx=i; idx<1024; idx+=256) f1r[idx] = ws[WS_F1 + (size_t)bs*1024 + idx];
    __syncthreads();
    const float* wr = W2 + (size_t)(l*256+i)*1024;
    float acc = fb2[l*256+i];
    for(int k=0;k<1024;k+=4){
        float4 w4 = *(const float4*)(wr+k);
        acc += w4.x*f1r[k]+w4.y*f1r[k+1]+w4.z*f1r[k+2]+w4.w*f1r[k+3];
    }
    float x = ws[WS_HB + (size_t)bs*256 + i] + acc;
    red[i]=x; __syncthreads();
    for(int off=128;off>0;off>>=1){ if(i<off) red[i]+=red[i+off]; __syncthreads(); }
    float m = red[0]*(1.0f/256.0f); __syncthreads();
    float d = x-m;
    red[i]=d*d; __syncthreads();
    for(int off=128;off>0;off>>=1){ if(i<off) red[i]+=red[i+off]; __syncthreads(); }
    float v = red[0]*(1.0f/256.0f);
    float y = d / sqrtf(v+1e-5f);
    ws[WS_HB + (size_t)bs*256 + i] = y*g2[l*256+i] + b2v[l*256+i];
}

__global__ __launch_bounds__(256) void k_latent(float* ws){
    int b=blockIdx.x, i=threadIdx.x; float a=0.f;
#pragma unroll
    for(int s=0;s<16;++s) a += ws[WS_HB + (size_t)(b*16+s)*256 + i];
    ws[WS_LAT + (size_t)b*256 + i] = a*(1.0f/16.0f);
}

// ======================= GRU prep ==========================================

__global__ __launch_bounds__(768) void k_gi0(const float* Wih, const float* bih,
                                             float* ws){
    __shared__ float lat[256];
    int b=blockIdx.x, j=threadIdx.x;
    if(j<256) lat[j]=ws[WS_LAT + (size_t)b*256 + j];
    __syncthreads();
    const float* wr = Wih + (size_t)j*256;
    float acc = bih[j];
    for(int k=0;k<256;k+=4){
        float4 w4=*(const float4*)(wr+k);
        acc += w4.x*lat[k]+w4.y*lat[k+1]+w4.z*lat[k+2]+w4.w*lat[k+3];
    }
    ws[WS_GI0 + (size_t)b*768 + j] = acc;
}

// Fused matrix M (1024x256) rows:  0..255 r-gate (A+Whh), 256..511 z-gate
// (A+Whh), 512..767 A_n, 768..1023 Whh_n ; A = Wih @ out_W.
__global__ __launch_bounds__(256) void k_prepm(const float* Wih, const float* Whh,
                                               const float* bih, const float* bhh,
                                               const float* outW, const float* outb,
                                               float* ws){
    __shared__ float wrow[256]; __shared__ float red[256]; __shared__ float mrow[256];
    int r=blockIdx.x, c=threadIdx.x;
    bool hasA = (r<768);
    wrow[c] = hasA ? Wih[(size_t)r*256+c] : 0.0f;
    __syncthreads();
    float m;
    if(hasA){
        float a=0.f;
        for(int k=0;k<256;++k) a += wrow[k]*outW[(size_t)k*256+c];
        if(r<512) a += Whh[(size_t)r*256+c];
        m=a;
    } else {
        m = Whh[(size_t)(r-256)*256+c];
    }
    mrow[c]=m;
    red[c] = wrow[c]*outb[c];
    __syncthreads();
    for(int off=128;off>0;off>>=1){ if(c<off) red[c]+=red[c+off]; __syncthreads(); }
    if(c==0){
        float cv;
        if(r<512)       cv = red[0] + bih[r] + bhh[r];
        else if(r<768)  cv = red[0] + bih[r];
        else            cv = bhh[r-256];
        ws[WS_CV + r] = cv;
    }
    if(c<128){
        union{ _Float16 h[2]; uint_t u; } pk;
        pk.h[0]=(_Float16)mrow[2*c]; pk.h[1]=(_Float16)mrow[2*c+1];
        ((uint_t*)(ws))[WS_M + (size_t)r*128 + c] = pk.u;
    }
}

// ======================= sequential GRU chain ==============================
// 16 blocks (one per batch chain), 512 threads.  tid -> q = col-quarter
// (64 cols), g = row-group.  Thread handles rows g+128*s, s=0..7:
// s=0..5 weights in VGPRs, s=6..7 in LDS.  h (256 f16) broadcast via LDS.

#define DOT4(A,W0,W1,W2,W3) { A=dot2f(W0,hv.x,A); A=dot2f(W1,hv.y,A); A=dot2f(W2,hv.z,A); A=dot2f(W3,hv.w,A); }
#define RED2(A) { A += __shfl_xor(A,1); A += __shfl_xor(A,2); }

__global__ __launch_bounds__(512) void k_chain(const float* bhh, float* ws){
    __shared__ uint_t wlds[2*8*512*4];    // 128 KB: [slice][cc][tid][4]
    __shared__ uint_t h16u[128];          // 256 f16 of current h
    int tid = threadIdx.x;
    int b   = blockIdx.x;
    int q   = tid & 3, g = tid >> 2;
    const uint_t* Mdw = (const uint_t*)ws + WS_M;

    // load 6 register slices
    uint_t w[6][32];
#pragma unroll
    for(int s=0;s<6;++s){
        const uint_t* src = Mdw + (size_t)(g + 128*s)*128 + q*32;
#pragma unroll
        for(int k=0;k<32;++k) w[s][k] = src[k];
    }
    // 2 LDS slices (s=6,7), layout interleaved for conflict-free b128 reads
#pragma unroll
    for(int s=0;s<2;++s){
        const uint_t* src = Mdw + (size_t)(g + 128*(6+s))*128 + q*32;
#pragma unroll
        for(int cc=0;cc<8;++cc)
#pragma unroll
            for(int k=0;k<4;++k)
                wlds[(((size_t)s*8+cc)*512 + tid)*4 + k] = src[cc*4+k];
    }

    float C8[8];
    float hp0=0.f, hp1=0.f;
    unsigned short* h16s = (unsigned short*)h16u;
    if(q==0){
#pragma unroll
        for(int s=0;s<8;++s) C8[s] = ws[WS_CV + g + 128*s];
        const float* gi = ws + WS_GI0 + (size_t)b*768;
        // step 0: h0 = 0, x0 = latent  ->  gh = bhh
        float r0 = sigf(gi[g]     + bhh[g]);
        float z0 = sigf(gi[256+g] + bhh[256+g]);
        float n0 = tanh_fast(gi[512+g] + r0*bhh[512+g]);
        hp0 = (1.0f-z0)*n0;
        float r1 = sigf(gi[128+g] + bhh[128+g]);
        float z1 = sigf(gi[384+g] + bhh[384+g]);
        float n1 = tanh_fast(gi[640+g] + r1*bhh[640+g]);
        hp1 = (1.0f-z1)*n1;
        h16s[g]     = f2hb(hp0);
        h16s[g+128] = f2hb(hp1);
        float* hs = ws + WS_HSEQ + (size_t)b*256;   // t = 0
        hs[g]=hp0; hs[g+128]=hp1;
    }
    __syncthreads();

    const uint_t* h16d = h16u;
    for(int t=1; t<1028; ++t){
        float a0=0,a1=0,a2=0,a3=0,a4=0,a5=0,a6=0,a7=0;
#pragma unroll
        for(int cc=0;cc<8;++cc){
            uint4 hv = *(const uint4*)(h16d + q*32 + cc*4);
            uint4 wa = *(const uint4*)(&wlds[(((size_t)0*8+cc)*512 + tid)*4]);
            uint4 wb = *(const uint4*)(&wlds[(((size_t)1*8+cc)*512 + tid)*4]);
            DOT4(a0, w[0][cc*4], w[0][cc*4+1], w[0][cc*4+2], w[0][cc*4+3]);
            DOT4(a1, w[1][cc*4], w[1][cc*4+1], w[1][cc*4+2], w[1][cc*4+3]);
            DOT4(a2, w[2][cc*4], w[2][cc*4+1], w[2][cc*4+2], w[2][cc*4+3]);
            DOT4(a3, w[3][cc*4], w[3][cc*4+1], w[3][cc*4+2], w[3][cc*4+3]);
            DOT4(a4, w[4][cc*4], w[4][cc*4+1], w[4][cc*4+2], w[4][cc*4+3]);
            DOT4(a5, w[5][cc*4], w[5][cc*4+1], w[5][cc*4+2], w[5][cc*4+3]);
            DOT4(a6, wa.x, wa.y, wa.z, wa.w);
            DOT4(a7, wb.x, wb.y, wb.z, wb.w);
        }
        RED2(a0); RED2(a1); RED2(a2); RED2(a3);
        RED2(a4); RED2(a5); RED2(a6); RED2(a7);
        __syncthreads();   // all h16 reads of step t done
        if(q==0){
            float r0 = sigf(a0 + C8[0]);
            float z0 = sigf(a2 + C8[2]);
            float n0 = tanh_fast(a4 + C8[4] + r0*(a6 + C8[6]));
            hp0 = (1.0f-z0)*n0 + z0*hp0;
            float r1 = sigf(a1 + C8[1]);
            float z1 = sigf(a3 + C8[3]);
            float n1 = tanh_fast(a5 + C8[5] + r1*(a7 + C8[7]));
            hp1 = (1.0f-z1)*n1 + z1*hp1;
            h16s[g]     = f2hb(hp0);
            h16s[g+128] = f2hb(hp1);
            float* hs = ws + WS_HSEQ + ((size_t)t*16 + b)*256;
            hs[g]=hp0; hs[g+128]=hp1;
        }
        __syncthreads();   // new h visible
    }
}

// ======================= epilogue GEMM =====================================
// OUT[b][t*256+j] = sum_c out_W[j][c]*HSEQ[t][b][c] + out_b[j]
__global__ __launch_bounds__(256) void k_epi(const float* outW, const float* outb,
                                             const float* ws, float* out){
    __shared__ float ht[16][256];
    int t = blockIdx.x, j = threadIdx.x;
    for(int idx=j; idx<4096; idx+=256)
        ht[idx>>8][idx&255] = ws[WS_HSEQ + (size_t)t*4096 + idx];
    __syncthreads();
    const float* wr = outW + (size_t)j*256;
    float bias = outb[j];
    float acc[16];
#pragma unroll
    for(int bb=0;bb<16;++bb) acc[bb]=bias;
    for(int k=0;k<256;k+=4){
        float4 w4 = *(const float4*)(wr+k);
#pragma unroll
        for(int bb=0;bb<16;++bb)
            acc[bb] += w4.x*ht[bb][k]+w4.y*ht[bb][k+1]+w4.z*ht[bb][k+2]+w4.w*ht[bb][k+3];
    }
#pragma unroll
    for(int bb=0;bb<16;++bb)
        out[(size_t)bb*263168 + (size_t)t*256 + j] = acc[bb];
}

// ======================= launch ============================================

extern "C" void kernel_launch(void* const* d_in, const int* in_sizes, int n_in,
                              void* d_out, int out_size, void* d_ws, size_t ws_size,
                              hipStream_t stream){
    const float* gs   = (const float*)d_in[0];
    const float* eW   = (const float*)d_in[1];
    const float* eb   = (const float*)d_in[2];
    const float* qkvW = (const float*)d_in[3];
    const float* qkvb = (const float*)d_in[4];
    const float* aoW  = (const float*)d_in[5];
    const float* aob  = (const float*)d_in[6];
    const float* g1   = (const float*)d_in[7];
    const float* b1   = (const float*)d_in[8];
    const float* g2   = (const float*)d_in[9];
    const float* b2   = (const float*)d_in[10];
    const float* W1   = (const float*)d_in[11];
    const float* fb1  = (const float*)d_in[12];
    const float* W2   = (const float*)d_in[13];
    const float* fb2  = (const float*)d_in[14];
    const float* Wih  = (const float*)d_in[15];
    const float* Whh  = (const float*)d_in[16];
    const float* bih  = (const float*)d_in[17];
    const float* bhh  = (const float*)d_in[18];
    const float* outW = (const float*)d_in[19];
    const float* outb = (const float*)d_in[20];
    float* ws  = (float*)d_ws;
    float* out = (float*)d_out;

    k_embed<<<256,256,0,stream>>>(gs,eW,eb,ws);
    for(int l=0;l<2;++l){
        k_qkv    <<<dim3(16,3),256,0,stream>>>(qkvW,qkvb,ws,l);
        k_attn   <<<64,256,0,stream>>>(ws);
        k_ao_ln  <<<256,256,0,stream>>>(aoW,aob,g1,b1,ws,l);
        k_ffn1   <<<dim3(16,4),256,0,stream>>>(W1,fb1,ws,l);
        k_ffn2_ln<<<256,256,0,stream>>>(W2,fb2,g2,b2,ws,l);
    }
    k_latent<<<16,256,0,stream>>>(ws);
    k_gi0   <<<16,768,0,stream>>>(Wih,bih,ws);
    k_prepm <<<1024,256,0,stream>>>(Wih,Whh,bih,bhh,outW,outb,ws);
    k_chain <<<16,512,0,stream>>>(bhh,ws);
    k_epi   <<<1028,256,0,stream>>>(outW,outb,ws,out);
}

// Round 2
// 2118.468 us; speedup vs baseline: 1.0990x; 1.0990x over previous
//
#include <hip/hip_runtime.h>
#include <hip/hip_fp16.h>

// ---------------------------------------------------------------------------
// GenomeDecoder: transformer encoder (tiny) -> 1028 sequential GRU steps ->
// output chunks.  Chunk feedback folded into recurrence (x_t = out_W@h_t+out_b
// => A = Wih@out_W absorbed), r/z gate rows pre-summed -> one 1024x256 f16
// matvec per step.  16 CUs, one batch chain each; 6/8 weight slices in
// VGPR/AGPR, 2/8 in LDS.  R2: padded h layout (no 4-way bank conflict),
// DPP quad reduction (off the LDS pipe), double-buffered h (1 barrier/step).
// ---------------------------------------------------------------------------

typedef _Float16 f16x2 __attribute__((ext_vector_type(2)));
typedef unsigned int uint_t;

// ---- workspace layout (float indices) ----
static constexpr size_t WS_HB   = 0;
static constexpr size_t WS_QKV  = 65536;
static constexpr size_t WS_AO   = 262144;
static constexpr size_t WS_F1   = 327680;
static constexpr size_t WS_LAT  = 589824;
static constexpr size_t WS_GI0  = 593920;
static constexpr size_t WS_CV   = 606208;
static constexpr size_t WS_M    = 607232;   // 131072 dword slots (f16x2 packed)
static constexpr size_t WS_HSEQ = 738304;   // 1028*16*256 floats

#if defined(__has_builtin)
#if __has_builtin(__builtin_amdgcn_fdot2)
#define HAVE_FDOT2 1
#endif
#endif

__device__ inline f16x2 u2h(uint_t u){ union{uint_t u; f16x2 h;} c; c.u=u; return c.h; }

__device__ inline float dot2f(uint_t w, uint_t h, float acc){
#ifdef HAVE_FDOT2
    return __builtin_amdgcn_fdot2(u2h(w), u2h(h), acc, false);
#else
    f16x2 a=u2h(w), b=u2h(h);
    return acc + (float)a.x*(float)b.x + (float)a.y*(float)b.y;
#endif
}

__device__ inline unsigned short f2hb(float x){
    union{ _Float16 h; unsigned short u; } c; c.h = (_Float16)x; return c.u;
}
__device__ inline float sigf(float x){ return 1.0f/(1.0f+__expf(-x)); }
__device__ inline float tanh_fast(float x){ float e=__expf(2.0f*x); return (e-1.0f)/(e+1.0f); }

// quad reduction on the VALU pipe (DPP quad_perm), not ds_swizzle.
__device__ inline float quad_reduce_add(float a){
    union{ float f; int i; } c0, c1;
    c0.f = a;
    c1.i = __builtin_amdgcn_update_dpp(0, c0.i, 0xB1, 0xF, 0xF, false); // xor 1
    float a1 = a + c1.f;
    c0.f = a1;
    c1.i = __builtin_amdgcn_update_dpp(0, c0.i, 0x4E, 0xF, 0xF, false); // xor 2
    return a1 + c1.f;
}

// ======================= transformer front-end =============================

__global__ __launch_bounds__(256) void k_embed(const float* gs, const float* eW,
                                               const float* eb, float* ws){
    int bs = blockIdx.x;            // b*16+s
    int i  = threadIdx.x;
    const float* g = gs + bs*16;
    float acc = eb[i];
#pragma unroll
    for(int d=0; d<16; ++d) acc += g[d]*eW[i*16+d];
    ws[WS_HB + (size_t)bs*256 + i] = acc;
}

__global__ __launch_bounds__(256) void k_qkv(const float* qkvW, const float* qkvb,
                                             float* ws, int l){
    __shared__ float hr[16][256];
    int b = blockIdx.x, jc = blockIdx.y;
    for(int idx=threadIdx.x; idx<4096; idx+=256)
        hr[idx>>8][idx&255] = ws[WS_HB + (size_t)(b*16+(idx>>8))*256 + (idx&255)];
    __syncthreads();
    int j = jc*256 + threadIdx.x;
    float bias = qkvb[l*768 + j];
    float acc[16];
#pragma unroll
    for(int s=0;s<16;++s) acc[s]=bias;
    const float* wr = qkvW + (size_t)(l*768 + j)*256;
    for(int k=0;k<256;k+=4){
        float4 w4 = *(const float4*)(wr+k);
#pragma unroll
        for(int s=0;s<16;++s)
            acc[s] += w4.x*hr[s][k] + w4.y*hr[s][k+1] + w4.z*hr[s][k+2] + w4.w*hr[s][k+3];
    }
    for(int s=0;s<16;++s) ws[WS_QKV + (size_t)(b*16+s)*768 + j] = acc[s];
}

__global__ __launch_bounds__(256) void k_attn(float* ws){
    __shared__ float ql[16][64], kl[16][64], vl[16][64], sc[16][16];
    int b = blockIdx.x>>2, hh = blockIdx.x&3;
    for(int idx=threadIdx.x; idx<1024; idx+=256){
        int s_=idx>>6, d=idx&63;
        const float* base = &ws[WS_QKV + (size_t)(b*16+s_)*768 + hh*64 + d];
        ql[s_][d]=base[0]; kl[s_][d]=base[256]; vl[s_][d]=base[512];
    }
    __syncthreads();
    int s = threadIdx.x>>4, t = threadIdx.x&15;
    float a=0.f;
#pragma unroll
    for(int d=0; d<64; ++d) a += ql[s][d]*kl[t][d];
    sc[s][t] = a*0.125f;
    __syncthreads();
    if(threadIdx.x<16){
        int r=threadIdx.x;
        float m=-1e30f;
#pragma unroll
        for(int tt=0;tt<16;++tt) m=fmaxf(m,sc[r][tt]);
        float e[16]; float sum=0.f;
#pragma unroll
        for(int tt=0;tt<16;++tt){ e[tt]=__expf(sc[r][tt]-m); sum+=e[tt]; }
        float inv=1.0f/sum;
#pragma unroll
        for(int tt=0;tt<16;++tt) sc[r][tt]=e[tt]*inv;
    }
    __syncthreads();
    int dg = (threadIdx.x&15)*4;
#pragma unroll
    for(int dd=0;dd<4;++dd){
        int d = dg+dd; float o=0.f;
#pragma unroll
        for(int tt=0;tt<16;++tt) o += sc[s][tt]*vl[tt][d];
        ws[WS_AO + (size_t)(b*16+s)*256 + hh*64 + d] = o;
    }
}

__global__ __launch_bounds__(256) void k_ao_ln(const float* aoW, const float* aob,
                                               const float* g1, const float* b1,
                                               float* ws, int l){
    __shared__ float ao[256]; __shared__ float red[256];
    int bs = blockIdx.x, i = threadIdx.x;
    ao[i] = ws[WS_AO + (size_t)bs*256 + i];
    __syncthreads();
    const float* wr = aoW + (size_t)(l*256+i)*256;
    float acc = aob[l*256+i];
    for(int k=0;k<256;k+=4){
        float4 w4 = *(const float4*)(wr+k);
        acc += w4.x*ao[k]+w4.y*ao[k+1]+w4.z*ao[k+2]+w4.w*ao[k+3];
    }
    float x = ws[WS_HB + (size_t)bs*256 + i] + acc;
    red[i]=x; __syncthreads();
    for(int off=128;off>0;off>>=1){ if(i<off) red[i]+=red[i+off]; __syncthreads(); }
    float m = red[0]*(1.0f/256.0f); __syncthreads();
    float d = x-m;
    red[i]=d*d; __syncthreads();
    for(int off=128;off>0;off>>=1){ if(i<off) red[i]+=red[i+off]; __syncthreads(); }
    float v = red[0]*(1.0f/256.0f);
    float y = d / sqrtf(v+1e-5f);
    ws[WS_HB + (size_t)bs*256 + i] = y*g1[l*256+i] + b1[l*256+i];
}

__global__ __launch_bounds__(256) void k_ffn1(const float* W1, const float* fb1,
                                              float* ws, int l){
    __shared__ float hr[16][256];
    int b = blockIdx.x, jc = blockIdx.y;
    for(int idx=threadIdx.x; idx<4096; idx+=256)
        hr[idx>>8][idx&255] = ws[WS_HB + (size_t)(b*16+(idx>>8))*256 + (idx&255)];
    __syncthreads();
    int j = jc*256 + threadIdx.x;
    float bias = fb1[l*1024+j];
    float acc[16];
#pragma unroll
    for(int s=0;s<16;++s) acc[s]=bias;
    const float* wr = W1 + (size_t)(l*1024+j)*256;
    for(int k=0;k<256;k+=4){
        float4 w4 = *(const float4*)(wr+k);
#pragma unroll
        for(int s=0;s<16;++s)
            acc[s] += w4.x*hr[s][k] + w4.y*hr[s][k+1] + w4.z*hr[s][k+2] + w4.w*hr[s][k+3];
    }
    for(int s=0;s<16;++s)
        ws[WS_F1 + (size_t)(b*16+s)*1024 + j] = fmaxf(acc[s],0.0f);
}

__global__ __launch_bounds__(256) void k_ffn2_ln(const float* W2, const float* fb2,
                                                 const float* g2, const float* b2v,
                                                 float* ws, int l){
    __shared__ float f1r[1024]; __shared__ float red[256];
    int bs = blockIdx.x, i = threadIdx.x;
    for(int idx=i; idx<1024; idx+=256) f1r[idx] = ws[WS_F1 + (size_t)bs*1024 + idx];
    __syncthreads();
    const float* wr = W2 + (size_t)(l*256+i)*1024;
    float acc = fb2[l*256+i];
    for(int k=0;k<1024;k+=4){
        float4 w4 = *(const float4*)(wr+k);
        acc += w4.x*f1r[k]+w4.y*f1r[k+1]+w4.z*f1r[k+2]+w4.w*f1r[k+3];
    }
    float x = ws[WS_HB + (size_t)bs*256 + i] + acc;
    red[i]=x; __syncthreads();
    for(int off=128;off>0;off>>=1){ if(i<off) red[i]+=red[i+off]; __syncthreads(); }
    float m = red[0]*(1.0f/256.0f); __syncthreads();
    float d = x-m;
    red[i]=d*d; __syncthreads();
    for(int off=128;off>0;off>>=1){ if(i<off) red[i]+=red[i+off]; __syncthreads(); }
    float v = red[0]*(1.0f/256.0f);
    float y = d / sqrtf(v+1e-5f);
    ws[WS_HB + (size_t)bs*256 + i] = y*g2[l*256+i] + b2v[l*256+i];
}

__global__ __launch_bounds__(256) void k_latent(float* ws){
    int b=blockIdx.x, i=threadIdx.x; float a=0.f;
#pragma unroll
    for(int s=0;s<16;++s) a += ws[WS_HB + (size_t)(b*16+s)*256 + i];
    ws[WS_LAT + (size_t)b*256 + i] = a*(1.0f/16.0f);
}

// ======================= GRU prep ==========================================

__global__ __launch_bounds__(768) void k_gi0(const float* Wih, const float* bih,
                                             float* ws){
    __shared__ float lat[256];
    int b=blockIdx.x, j=threadIdx.x;
    if(j<256) lat[j]=ws[WS_LAT + (size_t)b*256 + j];
    __syncthreads();
    const float* wr = Wih + (size_t)j*256;
    float acc = bih[j];
    for(int k=0;k<256;k+=4){
        float4 w4=*(const float4*)(wr+k);
        acc += w4.x*lat[k]+w4.y*lat[k+1]+w4.z*lat[k+2]+w4.w*lat[k+3];
    }
    ws[WS_GI0 + (size_t)b*768 + j] = acc;
}

// Fused matrix M (1024x256) rows:  0..255 r-gate (A+Whh), 256..511 z-gate
// (A+Whh), 512..767 A_n, 768..1023 Whh_n ; A = Wih @ out_W.
__global__ __launch_bounds__(256) void k_prepm(const float* Wih, const float* Whh,
                                               const float* bih, const float* bhh,
                                               const float* outW, const float* outb,
                                               float* ws){
    __shared__ float wrow[256]; __shared__ float red[256]; __shared__ float mrow[256];
    int r=blockIdx.x, c=threadIdx.x;
    bool hasA = (r<768);
    wrow[c] = hasA ? Wih[(size_t)r*256+c] : 0.0f;
    __syncthreads();
    float m;
    if(hasA){
        float a=0.f;
        for(int k=0;k<256;++k) a += wrow[k]*outW[(size_t)k*256+c];
        if(r<512) a += Whh[(size_t)r*256+c];
        m=a;
    } else {
        m = Whh[(size_t)(r-256)*256+c];
    }
    mrow[c]=m;
    red[c] = wrow[c]*outb[c];
    __syncthreads();
    for(int off=128;off>0;off>>=1){ if(c<off) red[c]+=red[c+off]; __syncthreads(); }
    if(c==0){
        float cv;
        if(r<512)       cv = red[0] + bih[r] + bhh[r];
        else if(r<768)  cv = red[0] + bih[r];
        else            cv = bhh[r-256];
        ws[WS_CV + r] = cv;
    }
    if(c<128){
        union{ _Float16 h[2]; uint_t u; } pk;
        pk.h[0]=(_Float16)mrow[2*c]; pk.h[1]=(_Float16)mrow[2*c+1];
        ((uint_t*)(ws))[WS_M + (size_t)r*128 + c] = pk.u;
    }
}

// ======================= sequential GRU chain ==============================
// 16 blocks (one per batch chain), 512 threads: q = tid&3 (64-col quarter),
// g = tid>>2 (row group).  Thread covers rows g+128*s, s=0..7: s=0..5 in
// VGPR/AGPR, s=6..7 in LDS.  h (256 f16) double-buffered in padded LDS
// (quarter stride 36 dwords -> distinct bank groups, broadcast conflict-free).

#define DOT4(A,W0,W1,W2,W3) { A=dot2f(W0,hv.x,A); A=dot2f(W1,hv.y,A); A=dot2f(W2,hv.z,A); A=dot2f(W3,hv.w,A); }

__global__ __launch_bounds__(512,2) void k_chain(const float* bhh, float* ws){
    __shared__ uint_t wlds[2*8*512*4];    // 128 KB: [slice][cc][tid][4]
    __shared__ uint_t hbuf[2][4*36];      // 2 x 576 B padded h buffers
    int tid = threadIdx.x;
    int b   = blockIdx.x;
    int q   = tid & 3, g = tid >> 2;
    const uint_t* Mdw = (const uint_t*)ws + WS_M;

    // 6 register slices (VGPR/AGPR resident)
    uint_t w[6][32];
#pragma unroll
    for(int s=0;s<6;++s){
        const uint_t* src = Mdw + (size_t)(g + 128*s)*128 + q*32;
#pragma unroll
        for(int k=0;k<32;++k) w[s][k] = src[k];
    }
    // 2 LDS slices (s=6,7), contiguous 16B per lane -> conflict-free b128
#pragma unroll
    for(int s=0;s<2;++s){
        const uint_t* src = Mdw + (size_t)(g + 128*(6+s))*128 + q*32;
#pragma unroll
        for(int cc=0;cc<8;++cc)
#pragma unroll
            for(int k=0;k<4;++k)
                wlds[(((size_t)s*8+cc)*512 + tid)*4 + k] = src[cc*4+k];
    }

    float C8[8];
#pragma unroll
    for(int s=0;s<8;++s) C8[s] = ws[WS_CV + g + 128*s];

    // step 0: h0 = 0, x0 = latent  ->  gh = bhh  (all lanes compute, q==0 stores)
    const float* gi = ws + WS_GI0 + (size_t)b*768;
    float r0 = sigf(gi[g]     + bhh[g]);
    float z0 = sigf(gi[256+g] + bhh[256+g]);
    float n0 = tanh_fast(gi[512+g] + r0*bhh[512+g]);
    float hp0 = (1.0f-z0)*n0;
    float r1 = sigf(gi[128+g] + bhh[128+g]);
    float z1 = sigf(gi[384+g] + bhh[384+g]);
    float n1 = tanh_fast(gi[640+g] + r1*bhh[640+g]);
    float hp1 = (1.0f-z1)*n1;
    if(q==0){
        unsigned short* hw = (unsigned short*)&hbuf[0][0];
        hw[(g>>6)*72     + (g&63)] = f2hb(hp0);   // component g
        hw[(2+(g>>6))*72 + (g&63)] = f2hb(hp1);   // component g+128
        float* hs = ws + WS_HSEQ + (size_t)b*256;
        hs[g]=hp0; hs[g+128]=hp1;
    }
    __syncthreads();

    int p = 0;
    for(int t=1; t<1028; ++t){
        const uint_t* hb = &hbuf[p][0];
        float a0=0,a1=0,a2=0,a3=0,a4=0,a5=0,a6=0,a7=0;
#pragma unroll
        for(int cc=0;cc<8;++cc){
            uint4 hv = *(const uint4*)(hb + q*36 + cc*4);
            uint4 wa = *(const uint4*)(&wlds[(((size_t)0*8+cc)*512 + tid)*4]);
            uint4 wb = *(const uint4*)(&wlds[(((size_t)1*8+cc)*512 + tid)*4]);
            DOT4(a0, w[0][cc*4], w[0][cc*4+1], w[0][cc*4+2], w[0][cc*4+3]);
            DOT4(a1, w[1][cc*4], w[1][cc*4+1], w[1][cc*4+2], w[1][cc*4+3]);
            DOT4(a2, w[2][cc*4], w[2][cc*4+1], w[2][cc*4+2], w[2][cc*4+3]);
            DOT4(a3, w[3][cc*4], w[3][cc*4+1], w[3][cc*4+2], w[3][cc*4+3]);
            DOT4(a4, w[4][cc*4], w[4][cc*4+1], w[4][cc*4+2], w[4][cc*4+3]);
            DOT4(a5, w[5][cc*4], w[5][cc*4+1], w[5][cc*4+2], w[5][cc*4+3]);
            DOT4(a6, wa.x, wa.y, wa.z, wa.w);
            DOT4(a7, wb.x, wb.y, wb.z, wb.w);
        }
        // quad reduction on VALU pipe (lanes 4g..4g+3 share g)
        a0=quad_reduce_add(a0); a1=quad_reduce_add(a1);
        a2=quad_reduce_add(a2); a3=quad_reduce_add(a3);
        a4=quad_reduce_add(a4); a5=quad_reduce_add(a5);
        a6=quad_reduce_add(a6); a7=quad_reduce_add(a7);
        // nonlinearity in all lanes (uniform within quad), stores predicated
        float rr0 = sigf(a0 + C8[0]);
        float zz0 = sigf(a2 + C8[2]);
        float nn0 = tanh_fast(a4 + C8[4] + rr0*(a6 + C8[6]));
        hp0 = (1.0f-zz0)*nn0 + zz0*hp0;
        float rr1 = sigf(a1 + C8[1]);
        float zz1 = sigf(a3 + C8[3]);
        float nn1 = tanh_fast(a5 + C8[5] + rr1*(a7 + C8[7]));
        hp1 = (1.0f-zz1)*nn1 + zz1*hp1;
        if(q==0){
            unsigned short* hw = (unsigned short*)&hbuf[p^1][0];
            hw[(g>>6)*72     + (g&63)] = f2hb(hp0);
            hw[(2+(g>>6))*72 + (g&63)] = f2hb(hp1);
            float* hs = ws + WS_HSEQ + ((size_t)t*16 + b)*256;
            hs[g]=hp0; hs[g+128]=hp1;
        }
        __syncthreads();   // new h visible; old buffer free for next overwrite
        p ^= 1;
    }
}

// ======================= epilogue GEMM =====================================
// OUT[b][t*256+j] = sum_c out_W[j][c]*HSEQ[t][b][c] + out_b[j]
__global__ __launch_bounds__(256) void k_epi(const float* outW, const float* outb,
                                             const float* ws, float* out){
    __shared__ float ht[16][256];
    int t = blockIdx.x, j = threadIdx.x;
    for(int idx=j; idx<4096; idx+=256)
        ht[idx>>8][idx&255] = ws[WS_HSEQ + (size_t)t*4096 + idx];
    __syncthreads();
    const float* wr = outW + (size_t)j*256;
    float bias = outb[j];
    float acc[16];
#pragma unroll
    for(int bb=0;bb<16;++bb) acc[bb]=bias;
    for(int k=0;k<256;k+=4){
        float4 w4 = *(const float4*)(wr+k);
#pragma unroll
        for(int bb=0;bb<16;++bb)
            acc[bb] += w4.x*ht[bb][k]+w4.y*ht[bb][k+1]+w4.z*ht[bb][k+2]+w4.w*ht[bb][k+3];
    }
#pragma unroll
    for(int bb=0;bb<16;++bb)
        out[(size_t)bb*263168 + (size_t)t*256 + j] = acc[bb];
}

// ======================= launch ============================================

extern "C" void kernel_launch(void* const* d_in, const int* in_sizes, int n_in,
                              void* d_out, int out_size, void* d_ws, size_t ws_size,
                              hipStream_t stream){
    const float* gs   = (const float*)d_in[0];
    const float* eW   = (const float*)d_in[1];
    const float* eb   = (const float*)d_in[2];
    const float* qkvW = (const float*)d_in[3];
    const float* qkvb = (const float*)d_in[4];
    const float* aoW  = (const float*)d_in[5];
    const float* aob  = (const float*)d_in[6];
    const float* g1   = (const float*)d_in[7];
    const float* b1   = (const float*)d_in[8];
    const float* g2   = (const float*)d_in[9];
    const float* b2   = (const float*)d_in[10];
    const float* W1   = (const float*)d_in[11];
    const float* fb1  = (const float*)d_in[12];
    const float* W2   = (const float*)d_in[13];
    const float* fb2  = (const float*)d_in[14];
    const float* Wih  = (const float*)d_in[15];
    const float* Whh  = (const float*)d_in[16];
    const float* bih  = (const float*)d_in[17];
    const float* bhh  = (const float*)d_in[18];
    const float* outW = (const float*)d_in[19];
    const float* outb = (const float*)d_in[20];
    float* ws  = (float*)d_ws;
    float* out = (float*)d_out;

    k_embed<<<256,256,0,stream>>>(gs,eW,eb,ws);
    for(int l=0;l<2;++l){
        k_qkv    <<<dim3(16,3),256,0,stream>>>(qkvW,qkvb,ws,l);
        k_attn   <<<64,256,0,stream>>>(ws);
        k_ao_ln  <<<256,256,0,stream>>>(aoW,aob,g1,b1,ws,l);
        k_ffn1   <<<dim3(16,4),256,0,stream>>>(W1,fb1,ws,l);
        k_ffn2_ln<<<256,256,0,stream>>>(W2,fb2,g2,b2,ws,l);
    }
    k_latent<<<16,256,0,stream>>>(ws);
    k_gi0   <<<16,768,0,stream>>>(Wih,bih,ws);
    k_prepm <<<1024,256,0,stream>>>(Wih,Whh,bih,bhh,outW,outb,ws);
    k_chain <<<16,512,0,stream>>>(bhh,ws);
    k_epi   <<<1028,256,0,stream>>>(outW,outb,ws,out);
}